// Round 10
// baseline (479.497 us; speedup 1.0000x reference)
//
#include <hip/hip_runtime.h>
#include <hip/hip_fp16.h>

#define NN 100000
#define EE 1600000
#define GG 256
#define EPS 1e-5f
#define KB2 ((NN + 511) >> 9)        // 196 scan blocks of 512 nodes
#define EPB 4096                     // edges per block (edge-pass kernels)
#define EBLK ((EE + EPB - 1) / EPB)  // 391
#define NB256 ((NN + 255) / 256)     // 391

// ---------- fp16 pack/unpack helpers (storage only; all math stays fp32) ----------
__device__ __forceinline__ unsigned int pack2(float x, float y) {
  __half2 h = __float22half2_rn(make_float2(x, y));
  return *reinterpret_cast<unsigned int*>(&h);
}
__device__ __forceinline__ uint2 pack4(float x, float y, float z, float w) {
  uint2 r;
  r.x = pack2(x, y);
  r.y = pack2(z, w);
  return r;
}
// unpack 8 halves (uint4) and accumulate into two float4s
__device__ __forceinline__ void add8(float4& a0, float4& a1, uint4 v) {
  __half2 h0 = *reinterpret_cast<__half2*>(&v.x);
  __half2 h1 = *reinterpret_cast<__half2*>(&v.y);
  __half2 h2 = *reinterpret_cast<__half2*>(&v.z);
  __half2 h3 = *reinterpret_cast<__half2*>(&v.w);
  float2 f0 = __half22float2(h0), f1 = __half22float2(h1);
  float2 f2 = __half22float2(h2), f3 = __half22float2(h3);
  a0.x += f0.x; a0.y += f0.y; a0.z += f1.x; a0.w += f1.y;
  a1.x += f2.x; a1.y += f2.y; a1.z += f3.x; a1.w += f3.y;
}

// ---------- inline-asm gathers: force deep in-flight batches ----------
__device__ __forceinline__ void gld16(uint4& d, const uint4* p) {
  asm volatile("global_load_dwordx4 %0, %1, off" : "=v"(d) : "v"(p));
}
__device__ __forceinline__ void gldf16(float4& d, const float4* p) {
  asm volatile("global_load_dwordx4 %0, %1, off" : "=v"(d) : "v"(p));
}

// ---------- CSR-direct preprocessing ----------
// pass 1: per-dst degree count (global atomics, table L2-resident)
__global__ void k_cnt(const int* __restrict__ ei, int* __restrict__ cnt) {
  int e0 = blockIdx.x * EPB;
  int t = threadIdx.x;
#pragma unroll
  for (int j = 0; j < 16; ++j) {
    int e = e0 + j * 256 + t;
    if (e < EE) atomicAdd(&cnt[ei[EE + e]], 1);
  }
}

// pass 2: block-local scan of 512 counts; also emits dinv and scaled xd
__global__ void k_scanA(const int* __restrict__ cnt, const float* __restrict__ x,
                        int* __restrict__ rowloc, int* __restrict__ bsum,
                        float* __restrict__ dinv, float4* __restrict__ xd) {
  __shared__ int s[512];
  int b = blockIdx.x, t = threadIdx.x;  // 512 threads
  int n = (b << 9) + t;
  int c = (n < NN) ? cnt[n] : 0;
  s[t] = c;
  __syncthreads();
  for (int off = 1; off < 512; off <<= 1) {
    int v = (t >= off) ? s[t - off] : 0;
    __syncthreads();
    s[t] += v;
    __syncthreads();
  }
  if (n < NN) {
    rowloc[n] = s[t] - c;  // block-local exclusive prefix
    float d = rsqrtf((float)c + 1.0f);
    dinv[n] = d;
    xd[n] = make_float4(x[n * 3] * d, x[n * 3 + 1] * d, x[n * 3 + 2] * d, 0.f);
  }
  if (t == 511) bsum[b] = s[t];
}

// pass 3: scan the 196 block sums
__global__ void k_scanB(const int* __restrict__ bsum, int* __restrict__ bbase) {
  __shared__ int s[256];
  int t = threadIdx.x;
  int v = (t < KB2) ? bsum[t] : 0;
  s[t] = v;
  __syncthreads();
  for (int off = 1; off < 256; off <<= 1) {
    int add = (t >= off) ? s[t - off] : 0;
    __syncthreads();
    s[t] += add;
    __syncthreads();
  }
  if (t < KB2) bbase[t] = s[t] - v;
}

// pass 4: global row pointers + scatter-fill init
__global__ void k_row(const int* __restrict__ rowloc, const int* __restrict__ cnt,
                      const int* __restrict__ bbase, int* __restrict__ row,
                      int* __restrict__ rowe, int* __restrict__ fill) {
  int n = blockIdx.x * 256 + threadIdx.x;
  if (n >= NN) return;
  int r = rowloc[n] + bbase[n >> 9];
  row[n] = r;
  fill[n] = r;
  rowe[n] = r + cnt[n];
}

// pass 5: single scatter of src indices into final csr
__global__ void k_scatter(const int* __restrict__ ei, int* __restrict__ fill,
                          int* __restrict__ csr) {
  int e0 = blockIdx.x * EPB;
  int t = threadIdx.x;
#pragma unroll
  for (int j = 0; j < 16; ++j) {
    int e = e0 + j * 256 + t;
    if (e < EE) {
      int ss = ei[e];
      int dd = ei[EE + e];
      int pos = atomicAdd(&fill[dd], 1);
      csr[pos] = ss;
    }
  }
}

// ---------- layer 0: fused 3-ch aggregate + 3->64 matmul + BN + ReLU + pre-scale ----------
__launch_bounds__(256, 4)
__global__ void k_agg3f(const float4* __restrict__ xd, const int* __restrict__ row,
                        const int* __restrict__ rowe, const int* __restrict__ csr,
                        const float* __restrict__ dinv,
                        const float* __restrict__ W, const float* __restrict__ b,
                        const float* __restrict__ gam, const float* __restrict__ bet,
                        const float* __restrict__ rm, const float* __restrict__ rv,
                        uint2* __restrict__ out) {
  int n = blockIdx.x * 256 + threadIdx.x;
  if (n >= NN) return;
  int s0 = row[n], s1 = rowe[n];
  float4 a = xd[n];
  float ax = a.x, ay = a.y, az = a.z;
  for (int i = s0; i < s1; i += 16) {
    int idx[16];
#pragma unroll
    for (int j = 0; j < 16; ++j) idx[j] = csr[min(i + j, s1 - 1)];
    float4 v[16];
#pragma unroll
    for (int j = 0; j < 16; ++j) gldf16(v[j], xd + idx[j]);
    asm volatile("s_waitcnt vmcnt(0)" ::: "memory");
    __builtin_amdgcn_sched_barrier(0);
    int rem = s1 - i;  // >= 1
#pragma unroll
    for (int j = 0; j < 16; ++j)
      if (j < rem) { ax += v[j].x; ay += v[j].y; az += v[j].z; }
  }
  float d = dinv[n];
  float t0 = ax * d, t1 = ay * d, t2 = az * d;
  const float4* W4 = (const float4*)W;
  const float4* b4 = (const float4*)b;
  const float4* g4p = (const float4*)gam;
  const float4* be4p = (const float4*)bet;
  const float4* rm4p = (const float4*)rm;
  const float4* rv4p = (const float4*)rv;
#pragma unroll
  for (int c4 = 0; c4 < 16; ++c4) {
    float4 w0 = W4[c4], w1 = W4[16 + c4], w2 = W4[32 + c4];
    float4 bb = b4[c4], g4 = g4p[c4], be4 = be4p[c4], rm4 = rm4p[c4], rv4 = rv4p[c4];
    float4 o;
    o.x = fmaf(t0, w0.x, fmaf(t1, w1.x, fmaf(t2, w2.x, bb.x)));
    o.y = fmaf(t0, w0.y, fmaf(t1, w1.y, fmaf(t2, w2.y, bb.y)));
    o.z = fmaf(t0, w0.z, fmaf(t1, w1.z, fmaf(t2, w2.z, bb.z)));
    o.w = fmaf(t0, w0.w, fmaf(t1, w1.w, fmaf(t2, w2.w, bb.w)));
    float scx = g4.x * rsqrtf(rv4.x + EPS), shx = be4.x - rm4.x * scx;
    float scy = g4.y * rsqrtf(rv4.y + EPS), shy = be4.y - rm4.y * scy;
    float scz = g4.z * rsqrtf(rv4.z + EPS), shz = be4.z - rm4.z * scz;
    float scw = g4.w * rsqrtf(rv4.w + EPS), shw = be4.w - rm4.w * scw;
    o.x = fmaxf(fmaf(o.x, scx, shx), 0.f) * d;
    o.y = fmaxf(fmaf(o.y, scy, shy), 0.f) * d;
    o.z = fmaxf(fmaf(o.z, scz, shz), 0.f) * d;
    o.w = fmaxf(fmaf(o.w, scw, shw), 0.f) * d;
    out[(size_t)n * 16 + c4] = pack4(o.x, o.y, o.z, o.w);
  }
}

// ---------- fused layer: 8-lane/row fp16 gather, asm-forced 9-deep load batches ----------
// MID=true: scale output by dinv, store fp16 (feeds next gather).
// MID=false: features never materialized — block-segment pooling reduction + atomics.
template <bool MID>
__launch_bounds__(256, 4)
__global__ void k_layer2(const uint4* __restrict__ xs, const int* __restrict__ row,
                         const int* __restrict__ rowe, const int* __restrict__ csr,
                         const float* __restrict__ dinv,
                         const float* __restrict__ W, const float* __restrict__ b,
                         const float* __restrict__ gam, const float* __restrict__ bet,
                         const float* __restrict__ rm, const float* __restrict__ rv,
                         uint4* __restrict__ outv, const int* __restrict__ bidx,
                         float* __restrict__ xsum, unsigned* __restrict__ xmaxu) {
  __shared__ float sh[32][68];
  int t = blockIdx.x * 256 + threadIdx.x;
  int n = t >> 3, sub = t & 7;        // 8 lanes per node, 32 nodes per block
  int local = threadIdx.x >> 3;
  // NN*8 = 800000 = 3125*256 exactly: no partial blocks, barrier-safe
  int s0 = row[n], s1 = rowe[n];
  float4 a0 = make_float4(0.f, 0.f, 0.f, 0.f);
  float4 a1 = make_float4(0.f, 0.f, 0.f, 0.f);
  add8(a0, a1, xs[(size_t)n * 8 + sub]);  // self term (pre-scaled by own dinv)
  if (s0 < s1) {
    int e = s0 + sub;
    int myidx = (e < s1) ? csr[e] : n;  // clamped lanes gather node n (cache hit)
    for (int i = s0; i < s1; i += 8) {
      int e2 = i + 8 + sub;
      int pre = csr[min(e2, s1 - 1)];  // next-round indices, in flight with gathers
      uint4 v0, v1, v2, v3, v4, v5, v6, v7;
      gld16(v0, xs + ((size_t)__shfl(myidx, 0, 8) * 8 + sub));
      gld16(v1, xs + ((size_t)__shfl(myidx, 1, 8) * 8 + sub));
      gld16(v2, xs + ((size_t)__shfl(myidx, 2, 8) * 8 + sub));
      gld16(v3, xs + ((size_t)__shfl(myidx, 3, 8) * 8 + sub));
      gld16(v4, xs + ((size_t)__shfl(myidx, 4, 8) * 8 + sub));
      gld16(v5, xs + ((size_t)__shfl(myidx, 5, 8) * 8 + sub));
      gld16(v6, xs + ((size_t)__shfl(myidx, 6, 8) * 8 + sub));
      gld16(v7, xs + ((size_t)__shfl(myidx, 7, 8) * 8 + sub));
      asm volatile("s_waitcnt vmcnt(0)" ::: "memory");
      __builtin_amdgcn_sched_barrier(0);
      int rem = s1 - i;  // >= 1, uniform within the 8-lane node group
      add8(a0, a1, v0);
      if (rem > 1) add8(a0, a1, v1);
      if (rem > 2) add8(a0, a1, v2);
      if (rem > 3) add8(a0, a1, v3);
      if (rem > 4) add8(a0, a1, v4);
      if (rem > 5) add8(a0, a1, v5);
      if (rem > 6) add8(a0, a1, v6);
      if (rem > 7) add8(a0, a1, v7);
      myidx = (e2 < s1) ? pre : n;
    }
  }
  float d = dinv[n];
  float4 w0 = make_float4(a0.x * d, a0.y * d, a0.z * d, a0.w * d);
  float4 w1 = make_float4(a1.x * d, a1.y * d, a1.z * d, a1.w * d);
  *(float4*)&sh[local][sub * 8] = w0;
  *(float4*)&sh[local][sub * 8 + 4] = w1;
  __syncthreads();
  const float4* W4 = (const float4*)W;
  float4 accA = ((const float4*)b)[sub * 2];
  float4 accB = ((const float4*)b)[sub * 2 + 1];
#pragma unroll 8
  for (int k = 0; k < 64; ++k) {
    float xv = sh[local][k];
    float4 wA = W4[k * 16 + sub * 2];
    float4 wB = W4[k * 16 + sub * 2 + 1];
    accA.x = fmaf(xv, wA.x, accA.x);
    accA.y = fmaf(xv, wA.y, accA.y);
    accA.z = fmaf(xv, wA.z, accA.z);
    accA.w = fmaf(xv, wA.w, accA.w);
    accB.x = fmaf(xv, wB.x, accB.x);
    accB.y = fmaf(xv, wB.y, accB.y);
    accB.z = fmaf(xv, wB.z, accB.z);
    accB.w = fmaf(xv, wB.w, accB.w);
  }
  float4 gA = ((const float4*)gam)[sub * 2], gB = ((const float4*)gam)[sub * 2 + 1];
  float4 beA = ((const float4*)bet)[sub * 2], beB = ((const float4*)bet)[sub * 2 + 1];
  float4 rmA = ((const float4*)rm)[sub * 2], rmB = ((const float4*)rm)[sub * 2 + 1];
  float4 rvA = ((const float4*)rv)[sub * 2], rvB = ((const float4*)rv)[sub * 2 + 1];
  float4 oA, oB;
  {
    float sc = gA.x * rsqrtf(rvA.x + EPS); oA.x = fmaxf(fmaf(accA.x, sc, beA.x - rmA.x * sc), 0.f);
    sc = gA.y * rsqrtf(rvA.y + EPS); oA.y = fmaxf(fmaf(accA.y, sc, beA.y - rmA.y * sc), 0.f);
    sc = gA.z * rsqrtf(rvA.z + EPS); oA.z = fmaxf(fmaf(accA.z, sc, beA.z - rmA.z * sc), 0.f);
    sc = gA.w * rsqrtf(rvA.w + EPS); oA.w = fmaxf(fmaf(accA.w, sc, beA.w - rmA.w * sc), 0.f);
    sc = gB.x * rsqrtf(rvB.x + EPS); oB.x = fmaxf(fmaf(accB.x, sc, beB.x - rmB.x * sc), 0.f);
    sc = gB.y * rsqrtf(rvB.y + EPS); oB.y = fmaxf(fmaf(accB.y, sc, beB.y - rmB.y * sc), 0.f);
    sc = gB.z * rsqrtf(rvB.z + EPS); oB.z = fmaxf(fmaf(accB.z, sc, beB.z - rmB.z * sc), 0.f);
    sc = gB.w * rsqrtf(rvB.w + EPS); oB.w = fmaxf(fmaf(accB.w, sc, beB.w - rmB.w * sc), 0.f);
  }
  if (MID) {
    uint4 r;
    r.x = pack2(oA.x * d, oA.y * d);
    r.y = pack2(oA.z * d, oA.w * d);
    r.z = pack2(oB.x * d, oB.y * d);
    r.w = pack2(oB.z * d, oB.w * d);
    outv[(size_t)n * 8 + sub] = r;
  } else {
    // fused pooling: reuse sh for output features, then per-segment reduce + atomics.
    __syncthreads();  // matmul reads of sh complete
    *(float4*)&sh[local][sub * 8] = oA;
    *(float4*)&sh[local][sub * 8 + 4] = oB;
    __syncthreads();
    int c = threadIdx.x & 63, q = threadIdx.x >> 6;  // channel, row-quarter
    int nb = blockIdx.x * 32 + q * 8;                // 8 consecutive nodes per quarter
    float ps = 0.f, pm = 0.f;
    int curg = bidx[nb];
#pragma unroll
    for (int r2 = 0; r2 < 8; ++r2) {
      int g = bidx[nb + r2];
      if (g != curg) {  // bidx sorted: few segments per block
        atomicAdd(&xsum[(size_t)curg * 64 + c], ps);
        atomicMax(&xmaxu[(size_t)curg * 64 + c], __float_as_uint(pm));
        ps = 0.f; pm = 0.f; curg = g;
      }
      float v = sh[q * 8 + r2][c];
      ps += v;
      pm = fmaxf(pm, v);
    }
    atomicAdd(&xsum[(size_t)curg * 64 + c], ps);
    atomicMax(&xmaxu[(size_t)curg * 64 + c], __float_as_uint(pm));  // v>=0: uint order == float order
  }
}

// ---------- final MLP over pooled [G,128] ----------
__device__ __forceinline__ int lower_bound(const int* __restrict__ b, int target) {
  int lo = 0, hi = NN;
  while (lo < hi) {
    int m = (lo + hi) >> 1;
    if (b[m] < target) lo = m + 1; else hi = m;
  }
  return lo;
}

__global__ void k_mlp(const float* __restrict__ xsum, const float* __restrict__ xmaxf,
                      const int* __restrict__ bidx,
                      const float* __restrict__ mW1, const float* __restrict__ mb1,
                      const float* __restrict__ mW2, const float* __restrict__ mb2,
                      const float* __restrict__ mW3, const float* __restrict__ mb3,
                      float* __restrict__ out) {
  __shared__ float xg[128], h1[32], h2[16];
  int g = blockIdx.x, t = threadIdx.x;  // 64 threads
  int lo = lower_bound(bidx, g);
  int hi = lower_bound(bidx, g + 1);
  float inv = 1.0f / fmaxf((float)(hi - lo), 1.0f);
  xg[t] = xsum[(size_t)g * 64 + t] * inv;
  xg[64 + t] = xmaxf[(size_t)g * 64 + t];  // stored as nonneg-float bit pattern
  __syncthreads();
  if (t < 32) {
    float a = mb1[t];
    for (int k = 0; k < 128; ++k) a = fmaf(xg[k], mW1[k * 32 + t], a);
    h1[t] = fmaxf(a, 0.f);
  }
  __syncthreads();
  if (t < 16) {
    float a = mb2[t];
    for (int k = 0; k < 32; ++k) a = fmaf(h1[k], mW2[k * 16 + t], a);
    h2[t] = fmaxf(a, 0.f);
  }
  __syncthreads();
  if (t == 0) {
    float a = mb3[0];
    for (int k = 0; k < 16; ++k) a = fmaf(h2[k], mW3[k], a);
    out[g] = a;
  }
}

extern "C" void kernel_launch(void* const* d_in, const int* in_sizes, int n_in,
                              void* d_out, int out_size, void* d_ws, size_t ws_size,
                              hipStream_t stream) {
  const float* x = (const float*)d_in[0];
  const int* ei = (const int*)d_in[1];
  const int* bidx = (const int*)d_in[2];
  const float *W[3], *b[3], *gam[3], *bet[3], *rm[3], *rv[3];
  for (int l = 0; l < 3; ++l) {
    W[l] = (const float*)d_in[3 + 6 * l];
    b[l] = (const float*)d_in[4 + 6 * l];
    gam[l] = (const float*)d_in[5 + 6 * l];
    bet[l] = (const float*)d_in[6 + 6 * l];
    rm[l] = (const float*)d_in[7 + 6 * l];
    rv[l] = (const float*)d_in[8 + 6 * l];
  }
  const float* mW1 = (const float*)d_in[21];
  const float* mb1 = (const float*)d_in[22];
  const float* mW2 = (const float*)d_in[23];
  const float* mb2 = (const float*)d_in[24];
  const float* mW3 = (const float*)d_in[25];
  const float* mb3 = (const float*)d_in[26];
  float* out = (float*)d_out;

  char* ws = (char*)d_ws;
  size_t off = 0;
  auto alloc = [&](size_t bytes) {
    void* p = ws + off;
    off = (off + bytes + 1023) & ~(size_t)1023;
    return p;
  };
  float* dinv = (float*)alloc(NN * 4);
  int* row = (int*)alloc(NN * 4);
  int* rowe = (int*)alloc(NN * 4);
  int* cnt = (int*)alloc(NN * 4);
  int* rowloc = (int*)alloc(NN * 4);
  int* fill = (int*)alloc(NN * 4);
  int* bsum = (int*)alloc(256 * 4);
  int* bbase = (int*)alloc(256 * 4);
  int* csr = (int*)alloc((size_t)EE * 4);
  float4* xd = (float4*)alloc((size_t)NN * 16);
  float* pool = (float*)alloc(GG * 64 * 4 * 2);       // xsum | xmax (contiguous 128 KB)
  float* xsum = pool;
  unsigned* xmaxu = (unsigned*)(pool + GG * 64);
  float* bufA = (float*)alloc((size_t)NN * 64 * 2);   // fp16 L0 out
  float* bufB = (float*)alloc((size_t)NN * 64 * 2);   // fp16 mid features

  hipMemsetAsync(cnt, 0, NN * 4, stream);
  hipMemsetAsync(pool, 0, GG * 64 * 4 * 2, stream);

  // CSR-direct graph build: count -> block scan -> top scan -> rows -> single scatter
  k_cnt<<<EBLK, 256, 0, stream>>>(ei, cnt);
  k_scanA<<<KB2, 512, 0, stream>>>(cnt, x, rowloc, bsum, dinv, xd);
  k_scanB<<<1, 256, 0, stream>>>(bsum, bbase);
  k_row<<<NB256, 256, 0, stream>>>(rowloc, cnt, bbase, row, rowe, fill);
  k_scatter<<<EBLK, 256, 0, stream>>>(ei, fill, csr);

  int nb8 = (NN * 8) / 256;  // 3125, exact

  // layer 0: fused aggregate + 3->64 matmul + BN + ReLU (pre-scaled fp16 out)
  k_agg3f<<<NB256, 256, 0, stream>>>(xd, row, rowe, csr, dinv, W[0], b[0], gam[0], bet[0],
                                     rm[0], rv[0], (uint2*)bufA);
  // layer 1: fp16 gather + fp32 matmul + BN + ReLU, pre-scaled fp16 out
  k_layer2<true><<<nb8, 256, 0, stream>>>((const uint4*)bufA, row, rowe, csr, dinv, W[1], b[1],
                                          gam[1], bet[1], rm[1], rv[1], (uint4*)bufB,
                                          bidx, xsum, xmaxu);
  // layer 2: fp16 gather + fp32 matmul + BN + ReLU, fused pooling (no feature store)
  k_layer2<false><<<nb8, 256, 0, stream>>>((const uint4*)bufB, row, rowe, csr, dinv, W[2], b[2],
                                           gam[2], bet[2], rm[2], rv[2], (uint4*)bufA,
                                           bidx, xsum, xmaxu);
  // final MLP over pooled features
  k_mlp<<<GG, 64, 0, stream>>>(xsum, (const float*)xmaxu, bidx, mW1, mb1, mW2, mb2,
                               mW3, mb3, out);
}

// Round 11
// 318.081 us; speedup vs baseline: 1.5075x; 1.5075x over previous
//
#include <hip/hip_runtime.h>
#include <hip/hip_fp16.h>

#define NN 100000
#define EE 1600000
#define GG 256
#define EPS 1e-5f
#define KB2 ((NN + 511) >> 9)        // 196 buckets of 512 dsts
#define BCAP 10240                   // per-bucket csr capacity (mean 8192: big headroom)
#define EPB 4096                     // edges per block (passA)
#define EBLK ((EE + EPB - 1) / EPB)  // 391
#define NB256 ((NN + 255) / 256)     // 391

// ---------- fp16 pack/unpack helpers (storage only; all math stays fp32) ----------
__device__ __forceinline__ unsigned int pack2(float x, float y) {
  __half2 h = __float22half2_rn(make_float2(x, y));
  return *reinterpret_cast<unsigned int*>(&h);
}
__device__ __forceinline__ uint2 pack4(float x, float y, float z, float w) {
  uint2 r;
  r.x = pack2(x, y);
  r.y = pack2(z, w);
  return r;
}
// unpack 8 halves (uint4) and accumulate into two float4s
__device__ __forceinline__ void add8(float4& a0, float4& a1, uint4 v) {
  __half2 h0 = *reinterpret_cast<__half2*>(&v.x);
  __half2 h1 = *reinterpret_cast<__half2*>(&v.y);
  __half2 h2 = *reinterpret_cast<__half2*>(&v.z);
  __half2 h3 = *reinterpret_cast<__half2*>(&v.w);
  float2 f0 = __half22float2(h0), f1 = __half22float2(h1);
  float2 f2 = __half22float2(h2), f3 = __half22float2(h3);
  a0.x += f0.x; a0.y += f0.y; a0.z += f1.x; a0.w += f1.y;
  a1.x += f2.x; a1.y += f2.y; a1.z += f3.x; a1.w += f3.y;
}

// ---------- inline-asm gathers: force deep in-flight batches ----------
__device__ __forceinline__ void gld16(uint4& d, const uint4* p) {
  asm volatile("global_load_dwordx4 %0, %1, off" : "=v"(d) : "v"(p));
}
__device__ __forceinline__ void gldf16(float4& d, const float4* p) {
  asm volatile("global_load_dwordx4 %0, %1, off" : "=v"(d) : "v"(p));
}

// ---------- stage 1: bucketed dump of packed (src<<9 | dst&511), fixed-capacity buckets ----------
// Locality-preserving: scatter confined to 40KB bucket regions (L2-resident), not random HBM.
__global__ void k_passA(const int* __restrict__ ei, int* __restrict__ bfill,
                        int* __restrict__ tmp) {
  __shared__ int cnt[KB2], cur[KB2], base[KB2];
  int t = threadIdx.x;
  for (int b = t; b < KB2; b += 256) { cnt[b] = 0; cur[b] = 0; }
  __syncthreads();
  int e0 = blockIdx.x * EPB;
  int myb[16], myp[16];
#pragma unroll
  for (int j = 0; j < 16; ++j) {
    int e = e0 + j * 256 + t;
    int bb = -1, pp = 0;
    if (e < EE) {
      int ss = ei[e];
      int dd = ei[EE + e];
      bb = dd >> 9;
      pp = (ss << 9) | (dd & 511);  // src:17b | dst_low:9b
    }
    myb[j] = bb;
    myp[j] = pp;
    if (bb >= 0) atomicAdd(&cnt[bb], 1);
  }
  __syncthreads();
  for (int b = t; b < KB2; b += 256)
    if (cnt[b] > 0) base[b] = b * BCAP + atomicAdd(&bfill[b], cnt[b]);
  __syncthreads();
#pragma unroll
  for (int j = 0; j < 16; ++j) {
    int bb = myb[j];
    if (bb >= 0) {
      int slot = base[bb] + atomicAdd(&cur[bb], 1);
      tmp[slot] = myp[j];
    }
  }
}

// ---------- stage 2: per-bucket hist+scan+scatter (LDS-staged); emits row/rowe, dinv, xd, csr ----------
__global__ void k_bucket(const int* __restrict__ tmp, const int* __restrict__ bfill,
                         const float* __restrict__ x, int* __restrict__ csr,
                         int* __restrict__ row, int* __restrict__ rowe,
                         float* __restrict__ dinv, float4* __restrict__ xd) {
  __shared__ int cnt[512], s[512], fillp[512];
  __shared__ int stmp[BCAP];
  int b = blockIdx.x, t = threadIdx.x;
  int nb = b << 9;
  int e0 = b * BCAP;
  int fill = bfill[b];
  cnt[t] = 0;
  cnt[t + 256] = 0;
  for (int e = t; e < fill; e += 256) stmp[e] = tmp[e0 + e];
  __syncthreads();
  for (int e = t; e < fill; e += 256) atomicAdd(&cnt[stmp[e] & 511], 1);
  __syncthreads();
  s[t] = cnt[t];
  s[t + 256] = cnt[t + 256];
  __syncthreads();
  for (int off = 1; off < 512; off <<= 1) {
    int i1 = t + 256;
    int v0 = (t >= off) ? s[t - off] : 0;
    int v1 = (i1 >= off) ? s[i1 - off] : 0;
    __syncthreads();
    s[t] += v0;
    s[i1] += v1;
    __syncthreads();
  }
#pragma unroll
  for (int k = 0; k < 2; ++k) {
    int i = t + k * 256;
    int excl = s[i] - cnt[i];
    fillp[i] = excl;
    int dst = nb + i;
    if (dst < NN) {
      row[dst] = e0 + excl;
      rowe[dst] = e0 + s[i];
      float d = rsqrtf((float)cnt[i] + 1.0f);
      dinv[dst] = d;
      xd[dst] = make_float4(x[dst * 3] * d, x[dst * 3 + 1] * d, x[dst * 3 + 2] * d, 0.f);
    }
  }
  __syncthreads();
  for (int e = t; e < fill; e += 256) {
    int ed = stmp[e];
    int slot = atomicAdd(&fillp[ed & 511], 1);
    csr[e0 + slot] = ed >> 9;  // plain src index
  }
}

// ---------- layer 0: fused 3-ch aggregate + 3->64 matmul + BN + ReLU + pre-scale ----------
__launch_bounds__(256, 4)
__global__ void k_agg3f(const float4* __restrict__ xd, const int* __restrict__ row,
                        const int* __restrict__ rowe, const int* __restrict__ csr,
                        const float* __restrict__ dinv,
                        const float* __restrict__ W, const float* __restrict__ b,
                        const float* __restrict__ gam, const float* __restrict__ bet,
                        const float* __restrict__ rm, const float* __restrict__ rv,
                        uint2* __restrict__ out) {
  int n = blockIdx.x * 256 + threadIdx.x;
  if (n >= NN) return;
  int s0 = row[n], s1 = rowe[n];
  float4 a = xd[n];
  float ax = a.x, ay = a.y, az = a.z;
  for (int i = s0; i < s1; i += 16) {
    int idx[16];
#pragma unroll
    for (int j = 0; j < 16; ++j) idx[j] = csr[min(i + j, s1 - 1)];
    float4 v[16];
#pragma unroll
    for (int j = 0; j < 16; ++j) gldf16(v[j], xd + idx[j]);
    asm volatile("s_waitcnt vmcnt(0)" ::: "memory");
    __builtin_amdgcn_sched_barrier(0);
    int rem = s1 - i;  // >= 1
#pragma unroll
    for (int j = 0; j < 16; ++j)
      if (j < rem) { ax += v[j].x; ay += v[j].y; az += v[j].z; }
  }
  float d = dinv[n];
  float t0 = ax * d, t1 = ay * d, t2 = az * d;
  const float4* W4 = (const float4*)W;
  const float4* b4 = (const float4*)b;
  const float4* g4p = (const float4*)gam;
  const float4* be4p = (const float4*)bet;
  const float4* rm4p = (const float4*)rm;
  const float4* rv4p = (const float4*)rv;
#pragma unroll
  for (int c4 = 0; c4 < 16; ++c4) {
    float4 w0 = W4[c4], w1 = W4[16 + c4], w2 = W4[32 + c4];
    float4 bb = b4[c4], g4 = g4p[c4], be4 = be4p[c4], rm4 = rm4p[c4], rv4 = rv4p[c4];
    float4 o;
    o.x = fmaf(t0, w0.x, fmaf(t1, w1.x, fmaf(t2, w2.x, bb.x)));
    o.y = fmaf(t0, w0.y, fmaf(t1, w1.y, fmaf(t2, w2.y, bb.y)));
    o.z = fmaf(t0, w0.z, fmaf(t1, w1.z, fmaf(t2, w2.z, bb.z)));
    o.w = fmaf(t0, w0.w, fmaf(t1, w1.w, fmaf(t2, w2.w, bb.w)));
    float scx = g4.x * rsqrtf(rv4.x + EPS), shx = be4.x - rm4.x * scx;
    float scy = g4.y * rsqrtf(rv4.y + EPS), shy = be4.y - rm4.y * scy;
    float scz = g4.z * rsqrtf(rv4.z + EPS), shz = be4.z - rm4.z * scz;
    float scw = g4.w * rsqrtf(rv4.w + EPS), shw = be4.w - rm4.w * scw;
    o.x = fmaxf(fmaf(o.x, scx, shx), 0.f) * d;
    o.y = fmaxf(fmaf(o.y, scy, shy), 0.f) * d;
    o.z = fmaxf(fmaf(o.z, scz, shz), 0.f) * d;
    o.w = fmaxf(fmaf(o.w, scw, shw), 0.f) * d;
    out[(size_t)n * 16 + c4] = pack4(o.x, o.y, o.z, o.w);
  }
}

// ---------- fused layer: 8-lane/row fp16 gather, asm-forced 9-deep load batches ----------
// MID=true: scale output by dinv, store fp16 (feeds next gather).
// MID=false: features never materialized — block-segment pooling reduction + atomics.
template <bool MID>
__launch_bounds__(256, 4)
__global__ void k_layer2(const uint4* __restrict__ xs, const int* __restrict__ row,
                         const int* __restrict__ rowe, const int* __restrict__ csr,
                         const float* __restrict__ dinv,
                         const float* __restrict__ W, const float* __restrict__ b,
                         const float* __restrict__ gam, const float* __restrict__ bet,
                         const float* __restrict__ rm, const float* __restrict__ rv,
                         uint4* __restrict__ outv, const int* __restrict__ bidx,
                         float* __restrict__ xsum, unsigned* __restrict__ xmaxu) {
  __shared__ float sh[32][68];
  int t = blockIdx.x * 256 + threadIdx.x;
  int n = t >> 3, sub = t & 7;        // 8 lanes per node, 32 nodes per block
  int local = threadIdx.x >> 3;
  // NN*8 = 800000 = 3125*256 exactly: no partial blocks, barrier-safe
  int s0 = row[n], s1 = rowe[n];
  float4 a0 = make_float4(0.f, 0.f, 0.f, 0.f);
  float4 a1 = make_float4(0.f, 0.f, 0.f, 0.f);
  add8(a0, a1, xs[(size_t)n * 8 + sub]);  // self term (pre-scaled by own dinv)
  if (s0 < s1) {
    int e = s0 + sub;
    int myidx = (e < s1) ? csr[e] : n;  // clamped lanes gather node n (cache hit)
    for (int i = s0; i < s1; i += 8) {
      int e2 = i + 8 + sub;
      int pre = csr[min(e2, s1 - 1)];  // next-round indices, in flight with gathers
      uint4 v0, v1, v2, v3, v4, v5, v6, v7;
      gld16(v0, xs + ((size_t)__shfl(myidx, 0, 8) * 8 + sub));
      gld16(v1, xs + ((size_t)__shfl(myidx, 1, 8) * 8 + sub));
      gld16(v2, xs + ((size_t)__shfl(myidx, 2, 8) * 8 + sub));
      gld16(v3, xs + ((size_t)__shfl(myidx, 3, 8) * 8 + sub));
      gld16(v4, xs + ((size_t)__shfl(myidx, 4, 8) * 8 + sub));
      gld16(v5, xs + ((size_t)__shfl(myidx, 5, 8) * 8 + sub));
      gld16(v6, xs + ((size_t)__shfl(myidx, 6, 8) * 8 + sub));
      gld16(v7, xs + ((size_t)__shfl(myidx, 7, 8) * 8 + sub));
      asm volatile("s_waitcnt vmcnt(0)" ::: "memory");
      __builtin_amdgcn_sched_barrier(0);
      int rem = s1 - i;  // >= 1, uniform within the 8-lane node group
      add8(a0, a1, v0);
      if (rem > 1) add8(a0, a1, v1);
      if (rem > 2) add8(a0, a1, v2);
      if (rem > 3) add8(a0, a1, v3);
      if (rem > 4) add8(a0, a1, v4);
      if (rem > 5) add8(a0, a1, v5);
      if (rem > 6) add8(a0, a1, v6);
      if (rem > 7) add8(a0, a1, v7);
      myidx = (e2 < s1) ? pre : n;
    }
  }
  float d = dinv[n];
  float4 w0 = make_float4(a0.x * d, a0.y * d, a0.z * d, a0.w * d);
  float4 w1 = make_float4(a1.x * d, a1.y * d, a1.z * d, a1.w * d);
  *(float4*)&sh[local][sub * 8] = w0;
  *(float4*)&sh[local][sub * 8 + 4] = w1;
  __syncthreads();
  const float4* W4 = (const float4*)W;
  float4 accA = ((const float4*)b)[sub * 2];
  float4 accB = ((const float4*)b)[sub * 2 + 1];
#pragma unroll 8
  for (int k = 0; k < 64; ++k) {
    float xv = sh[local][k];
    float4 wA = W4[k * 16 + sub * 2];
    float4 wB = W4[k * 16 + sub * 2 + 1];
    accA.x = fmaf(xv, wA.x, accA.x);
    accA.y = fmaf(xv, wA.y, accA.y);
    accA.z = fmaf(xv, wA.z, accA.z);
    accA.w = fmaf(xv, wA.w, accA.w);
    accB.x = fmaf(xv, wB.x, accB.x);
    accB.y = fmaf(xv, wB.y, accB.y);
    accB.z = fmaf(xv, wB.z, accB.z);
    accB.w = fmaf(xv, wB.w, accB.w);
  }
  float4 gA = ((const float4*)gam)[sub * 2], gB = ((const float4*)gam)[sub * 2 + 1];
  float4 beA = ((const float4*)bet)[sub * 2], beB = ((const float4*)bet)[sub * 2 + 1];
  float4 rmA = ((const float4*)rm)[sub * 2], rmB = ((const float4*)rm)[sub * 2 + 1];
  float4 rvA = ((const float4*)rv)[sub * 2], rvB = ((const float4*)rv)[sub * 2 + 1];
  float4 oA, oB;
  {
    float sc = gA.x * rsqrtf(rvA.x + EPS); oA.x = fmaxf(fmaf(accA.x, sc, beA.x - rmA.x * sc), 0.f);
    sc = gA.y * rsqrtf(rvA.y + EPS); oA.y = fmaxf(fmaf(accA.y, sc, beA.y - rmA.y * sc), 0.f);
    sc = gA.z * rsqrtf(rvA.z + EPS); oA.z = fmaxf(fmaf(accA.z, sc, beA.z - rmA.z * sc), 0.f);
    sc = gA.w * rsqrtf(rvA.w + EPS); oA.w = fmaxf(fmaf(accA.w, sc, beA.w - rmA.w * sc), 0.f);
    sc = gB.x * rsqrtf(rvB.x + EPS); oB.x = fmaxf(fmaf(accB.x, sc, beB.x - rmB.x * sc), 0.f);
    sc = gB.y * rsqrtf(rvB.y + EPS); oB.y = fmaxf(fmaf(accB.y, sc, beB.y - rmB.y * sc), 0.f);
    sc = gB.z * rsqrtf(rvB.z + EPS); oB.z = fmaxf(fmaf(accB.z, sc, beB.z - rmB.z * sc), 0.f);
    sc = gB.w * rsqrtf(rvB.w + EPS); oB.w = fmaxf(fmaf(accB.w, sc, beB.w - rmB.w * sc), 0.f);
  }
  if (MID) {
    uint4 r;
    r.x = pack2(oA.x * d, oA.y * d);
    r.y = pack2(oA.z * d, oA.w * d);
    r.z = pack2(oB.x * d, oB.y * d);
    r.w = pack2(oB.z * d, oB.w * d);
    outv[(size_t)n * 8 + sub] = r;
  } else {
    // fused pooling: reuse sh for output features, then per-segment reduce + atomics.
    __syncthreads();  // matmul reads of sh complete
    *(float4*)&sh[local][sub * 8] = oA;
    *(float4*)&sh[local][sub * 8 + 4] = oB;
    __syncthreads();
    int c = threadIdx.x & 63, q = threadIdx.x >> 6;  // channel, row-quarter
    int nb = blockIdx.x * 32 + q * 8;                // 8 consecutive nodes per quarter
    float ps = 0.f, pm = 0.f;
    int curg = bidx[nb];
#pragma unroll
    for (int r2 = 0; r2 < 8; ++r2) {
      int g = bidx[nb + r2];
      if (g != curg) {  // bidx sorted: few segments per block
        atomicAdd(&xsum[(size_t)curg * 64 + c], ps);
        atomicMax(&xmaxu[(size_t)curg * 64 + c], __float_as_uint(pm));
        ps = 0.f; pm = 0.f; curg = g;
      }
      float v = sh[q * 8 + r2][c];
      ps += v;
      pm = fmaxf(pm, v);
    }
    atomicAdd(&xsum[(size_t)curg * 64 + c], ps);
    atomicMax(&xmaxu[(size_t)curg * 64 + c], __float_as_uint(pm));  // v>=0: uint order == float order
  }
}

// ---------- final MLP over pooled [G,128] ----------
__device__ __forceinline__ int lower_bound(const int* __restrict__ b, int target) {
  int lo = 0, hi = NN;
  while (lo < hi) {
    int m = (lo + hi) >> 1;
    if (b[m] < target) lo = m + 1; else hi = m;
  }
  return lo;
}

__global__ void k_mlp(const float* __restrict__ xsum, const float* __restrict__ xmaxf,
                      const int* __restrict__ bidx,
                      const float* __restrict__ mW1, const float* __restrict__ mb1,
                      const float* __restrict__ mW2, const float* __restrict__ mb2,
                      const float* __restrict__ mW3, const float* __restrict__ mb3,
                      float* __restrict__ out) {
  __shared__ float xg[128], h1[32], h2[16];
  int g = blockIdx.x, t = threadIdx.x;  // 64 threads
  int lo = lower_bound(bidx, g);
  int hi = lower_bound(bidx, g + 1);
  float inv = 1.0f / fmaxf((float)(hi - lo), 1.0f);
  xg[t] = xsum[(size_t)g * 64 + t] * inv;
  xg[64 + t] = xmaxf[(size_t)g * 64 + t];  // stored as nonneg-float bit pattern
  __syncthreads();
  if (t < 32) {
    float a = mb1[t];
    for (int k = 0; k < 128; ++k) a = fmaf(xg[k], mW1[k * 32 + t], a);
    h1[t] = fmaxf(a, 0.f);
  }
  __syncthreads();
  if (t < 16) {
    float a = mb2[t];
    for (int k = 0; k < 32; ++k) a = fmaf(h1[k], mW2[k * 16 + t], a);
    h2[t] = fmaxf(a, 0.f);
  }
  __syncthreads();
  if (t == 0) {
    float a = mb3[0];
    for (int k = 0; k < 16; ++k) a = fmaf(h2[k], mW3[k], a);
    out[g] = a;
  }
}

extern "C" void kernel_launch(void* const* d_in, const int* in_sizes, int n_in,
                              void* d_out, int out_size, void* d_ws, size_t ws_size,
                              hipStream_t stream) {
  const float* x = (const float*)d_in[0];
  const int* ei = (const int*)d_in[1];
  const int* bidx = (const int*)d_in[2];
  const float *W[3], *b[3], *gam[3], *bet[3], *rm[3], *rv[3];
  for (int l = 0; l < 3; ++l) {
    W[l] = (const float*)d_in[3 + 6 * l];
    b[l] = (const float*)d_in[4 + 6 * l];
    gam[l] = (const float*)d_in[5 + 6 * l];
    bet[l] = (const float*)d_in[6 + 6 * l];
    rm[l] = (const float*)d_in[7 + 6 * l];
    rv[l] = (const float*)d_in[8 + 6 * l];
  }
  const float* mW1 = (const float*)d_in[21];
  const float* mb1 = (const float*)d_in[22];
  const float* mW2 = (const float*)d_in[23];
  const float* mb2 = (const float*)d_in[24];
  const float* mW3 = (const float*)d_in[25];
  const float* mb3 = (const float*)d_in[26];
  float* out = (float*)d_out;

  char* ws = (char*)d_ws;
  size_t off = 0;
  auto alloc = [&](size_t bytes) {
    void* p = ws + off;
    off = (off + bytes + 1023) & ~(size_t)1023;
    return p;
  };
  float* dinv = (float*)alloc(NN * 4);
  int* row = (int*)alloc(NN * 4);
  int* rowe = (int*)alloc(NN * 4);
  int* csr = (int*)alloc((size_t)KB2 * BCAP * 4);
  int* bfill = (int*)alloc(256 * 4);
  float4* xd = (float4*)alloc((size_t)NN * 16);
  float* pool = (float*)alloc(GG * 64 * 4 * 2);       // xsum | xmax (contiguous 128 KB)
  float* xsum = pool;
  unsigned* xmaxu = (unsigned*)(pool + GG * 64);
  float* bufA = (float*)alloc((size_t)NN * 64 * 4);   // fp16 L0 out / tmp alias
  float* bufB = (float*)alloc((size_t)NN * 64 * 2);   // fp16 mid features
  int* tmp = (int*)bufA;  // alias: tmp consumed by k_bucket before bufA is written

  hipMemsetAsync(bfill, 0, 256 * 4, stream);
  hipMemsetAsync(pool, 0, GG * 64 * 4 * 2, stream);

  // graph structure: bucketed dump (locality-preserving) -> per-bucket LDS-staged build
  k_passA<<<EBLK, 256, 0, stream>>>(ei, bfill, tmp);
  k_bucket<<<KB2, 256, 0, stream>>>(tmp, bfill, x, csr, row, rowe, dinv, xd);

  int nb8 = (NN * 8) / 256;  // 3125, exact

  // layer 0: fused aggregate + 3->64 matmul + BN + ReLU (pre-scaled fp16 out)
  k_agg3f<<<NB256, 256, 0, stream>>>(xd, row, rowe, csr, dinv, W[0], b[0], gam[0], bet[0],
                                     rm[0], rv[0], (uint2*)bufA);
  // layer 1: fp16 gather + fp32 matmul + BN + ReLU, pre-scaled fp16 out
  k_layer2<true><<<nb8, 256, 0, stream>>>((const uint4*)bufA, row, rowe, csr, dinv, W[1], b[1],
                                          gam[1], bet[1], rm[1], rv[1], (uint4*)bufB,
                                          bidx, xsum, xmaxu);
  // layer 2: fp16 gather + fp32 matmul + BN + ReLU, fused pooling (no feature store)
  k_layer2<false><<<nb8, 256, 0, stream>>>((const uint4*)bufB, row, rowe, csr, dinv, W[2], b[2],
                                           gam[2], bet[2], rm[2], rv[2], (uint4*)bufA,
                                           bidx, xsum, xmaxu);
  // final MLP over pooled features
  k_mlp<<<GG, 64, 0, stream>>>(xsum, (const float*)xmaxu, bidx, mW1, mb1, mW2, mb2,
                               mW3, mb3, out);
}